// Round 5
// baseline (484.284 us; speedup 1.0000x reference)
//
#include <hip/hip_runtime.h>
#include <hip/hip_bf16.h>
#include <stdint.h>

#define NROW 10000
#define DIM 128
#define NP 10048           // rows padded to multiple of 64
#define KSEL 15
#define NTILES (NP / 16)   // 628 j-tiles of 16

typedef __attribute__((ext_vector_type(4))) float f32x4;
typedef __attribute__((ext_vector_type(8))) short s16x8;
using bf16_t = __hip_bfloat16;

// ---------------------------------------------------------------- convert
// One wave per row: f32 -> bf16 (packed u32 stores), sqh = 1024 - 0.5*|x|^2
// (MFMA C-in, bias folded). Pad rows: zero data, sqh = -1e30 -> key clamps
// to 1.0, never top-15.
__global__ __launch_bounds__(256)
void knn_convert(const float* __restrict__ x0, const float* __restrict__ x1,
                 bf16_t* __restrict__ xb, float* __restrict__ sqh,
                 unsigned* __restrict__ counter)
{
    if (blockIdx.x == 0 && threadIdx.x == 0) *counter = 0u;
    const int rg   = blockIdx.x * 4 + (threadIdx.x >> 6);
    const int lane = threadIdx.x & 63;
    if (rg >= 2 * NP) return;
    const int m = rg >= NP ? 1 : 0;
    const int r = rg - m * NP;
    const float* src = m ? x1 : x0;
    uint32_t* dst = (uint32_t*)(xb + ((size_t)m * NP + (size_t)r) * DIM);

    float2 v = make_float2(0.f, 0.f);
    float  s = 0.f;
    if (r < NROW) {
        v = *(const float2*)(src + (size_t)r * DIM + lane * 2);
        s = v.x * v.x + v.y * v.y;
    }
    const uint32_t lo = (uint32_t)__bfloat16_as_ushort(__float2bfloat16(v.x));
    const uint32_t hi = (uint32_t)__bfloat16_as_ushort(__float2bfloat16(v.y));
    dst[lane] = lo | (hi << 16);
    #pragma unroll
    for (int off = 32; off; off >>= 1) s += __shfl_down(s, off);
    if (lane == 0) sqh[m * NP + r] = (r < NROW) ? fmaf(s, -0.5f, 1024.0f) : -1e30f;
}

// ---------------------------------------------------------------- main
// Key = dot(Xj,Xi) + 1024 - 0.5*sq[j] (bias in MFMA C-in), clamped >=1,
// packed as monotonic u32 with 10-bit chunk-local index in the low bits.
// Branchless top-15 per lane via 14x v_med3_u32 + 1 umax in 15 named regs.
#define INS(k, hi, lo) asm("v_med3_u32 %0, %1, %2, %0" : "+v"(lo) : "v"(k), "v"(hi))

template<int JC>
__global__ __launch_bounds__(256, 6)
void knn_topk(const bf16_t* __restrict__ xb, const float* __restrict__ sqh,
              uint32_t* __restrict__ pkey, uint16_t* __restrict__ pidx)
{
    __shared__ uint32_t lv[4][64][KSEL];   // keys only; j reconstructed from key bits

    const int m     = blockIdx.z;
    const int chunk = blockIdx.y;
    const int ib    = blockIdx.x * 64;
    const int wave  = threadIdx.x >> 6;
    const int lane  = threadIdx.x & 63;
    const int li    = lane & 15;
    const int g     = lane >> 4;

    const bf16_t* X  = xb + (size_t)m * NP * DIM;
    const float*  SQ = sqh + m * NP;

    const int i  = ib + wave * 16 + li;
    const int ic = i < NROW ? i : NROW - 1;

    // B fragments: lane holds B[k = kk*32 + g*8 + e][col = li] = X[i][k]
    s16x8 bfr[4];
    #pragma unroll
    for (int kk = 0; kk < 4; ++kk)
        bfr[kk] = *(const s16x8*)(X + (size_t)ic * DIM + kk * 32 + g * 8);

    uint32_t q0 = 0, q1 = 0, q2 = 0, q3 = 0, q4 = 0, q5 = 0, q6 = 0, q7 = 0,
             q8 = 0, q9 = 0, q10 = 0, q11 = 0, q12 = 0, q13 = 0, q14 = 0;

    const int t0 = (chunk * NTILES) / JC;
    const int t1 = ((chunk + 1) * NTILES) / JC;

    #pragma unroll 2
    for (int t = t0; t < t1; ++t) {
        const int jt = t * 16;
        f32x4 acc = *(const f32x4*)(SQ + jt + g * 4);   // 1024 - 0.5*sq[j]
        #pragma unroll
        for (int kk = 0; kk < 4; ++kk) {
            // A fragment: lane holds A[row = li][k = kk*32 + g*8 + e] = X[jt+li][k]
            const s16x8 afr = *(const s16x8*)(X + (size_t)(jt + li) * DIM + kk * 32 + g * 8);
            acc = __builtin_amdgcn_mfma_f32_16x16x32_bf16(afr, bfr[kk], acc, 0, 0, 0);
        }
        // C/D: col = li (the i), row = g*4 + r (the j-local).
        const uint32_t idxb = (uint32_t)((t - t0) << 2);
        #pragma unroll
        for (int r = 0; r < 4; ++r) {
            const float f = fmaxf(acc[r], 1.0f);          // padded j -> never selected
            const uint32_t b = __float_as_uint(f);        // positive float: u32-monotonic
            const uint32_t k = ((b + 512u) & 0xFFFFFC00u) | (idxb + (uint32_t)r);
            INS(k, q13, q14); INS(k, q12, q13); INS(k, q11, q12); INS(k, q10, q11);
            INS(k, q9,  q10); INS(k, q8,  q9);  INS(k, q7,  q8);  INS(k, q6,  q7);
            INS(k, q5,  q6);  INS(k, q4,  q5);  INS(k, q3,  q4);  INS(k, q2,  q3);
            INS(k, q1,  q2);  INS(k, q0,  q1);
            q0 = (q0 > k) ? q0 : k;
        }
    }

    lv[wave][lane][0]  = q0;  lv[wave][lane][1]  = q1;  lv[wave][lane][2]  = q2;
    lv[wave][lane][3]  = q3;  lv[wave][lane][4]  = q4;  lv[wave][lane][5]  = q5;
    lv[wave][lane][6]  = q6;  lv[wave][lane][7]  = q7;  lv[wave][lane][8]  = q8;
    lv[wave][lane][9]  = q9;  lv[wave][lane][10] = q10; lv[wave][lane][11] = q11;
    lv[wave][lane][12] = q12; lv[wave][lane][13] = q13; lv[wave][lane][14] = q14;
    __syncthreads();

    // 4-way merge of the lane-group lists for this i; write sorted 15.
    // j reconstructed from key's low 10 bits + winning group bg.
    if (g == 0 && i < NROW) {
        int p0 = 0, p1 = 0, p2 = 0, p3 = 0;
        uint32_t v0 = lv[wave][li][0];
        uint32_t v1 = lv[wave][16 + li][0];
        uint32_t v2 = lv[wave][32 + li][0];
        uint32_t v3 = lv[wave][48 + li][0];
        uint32_t* ov = pkey + (((size_t)m * JC + chunk) * NROW + i) * KSEL;
        uint16_t* oi = pidx + (((size_t)m * JC + chunk) * NROW + i) * KSEL;
        #pragma unroll
        for (int t = 0; t < KSEL; ++t) {
            uint32_t bv = v0; int bg = 0;
            if (v1 > bv) { bv = v1; bg = 1; }
            if (v2 > bv) { bv = v2; bg = 2; }
            if (v3 > bv) { bv = v3; bg = 3; }
            const uint32_t id = bv & 1023u;
            const int j = (t0 + (int)(id >> 2)) * 16 + bg * 4 + (int)(id & 3u);
            if      (bg == 0) { p0++; v0 = p0 < KSEL ? lv[wave][li][p0]      : 0u; }
            else if (bg == 1) { p1++; v1 = p1 < KSEL ? lv[wave][16 + li][p1] : 0u; }
            else if (bg == 2) { p2++; v2 = p2 < KSEL ? lv[wave][32 + li][p2] : 0u; }
            else              { p3++; v3 = p3 < KSEL ? lv[wave][48 + li][p3] : 0u; }
            ov[t] = bv; oi[t] = (uint16_t)j;
        }
    }
}

// ---------------------------------------------------------------- merge + count
template<int JC>
__global__ __launch_bounds__(256)
void knn_merge_count(const uint32_t* __restrict__ pkey, const uint16_t* __restrict__ pidx,
                     unsigned* __restrict__ counter)
{
    __shared__ int wsum[4];
    const int i    = blockIdx.x * 256 + threadIdx.x;
    const int lane = threadIdx.x & 63;
    const int wave = threadIdx.x >> 6;

    int cnt = 0;
    if (i < NROW) {
        int ids[2][KSEL];
        #pragma unroll
        for (int m = 0; m < 2; ++m) {
            const uint32_t* pv = pkey + (size_t)m * JC * NROW * KSEL;
            const uint16_t* px = pidx + (size_t)m * JC * NROW * KSEL;
            uint32_t v[JC]; int p[JC];
            #pragma unroll
            for (int gg = 0; gg < JC; ++gg) {
                p[gg] = 0;
                v[gg] = pv[((size_t)gg * NROW + i) * KSEL];
            }
            #pragma unroll
            for (int t = 0; t < KSEL; ++t) {
                uint32_t bv = v[0]; int bg = 0;
                #pragma unroll
                for (int gg = 1; gg < JC; ++gg) if (v[gg] > bv) { bv = v[gg]; bg = gg; }
                int j = 0;
                #pragma unroll
                for (int gg = 0; gg < JC; ++gg)
                    if (gg == bg) j = (int)px[((size_t)gg * NROW + i) * KSEL + p[gg]];
                ids[m][t] = j;
                #pragma unroll
                for (int gg = 0; gg < JC; ++gg)
                    if (gg == bg) {
                        p[gg]++;
                        v[gg] = p[gg] < KSEL ? pv[((size_t)gg * NROW + i) * KSEL + p[gg]] : 0u;
                    }
            }
        }
        #pragma unroll
        for (int a = 0; a < KSEL; ++a)
            #pragma unroll
            for (int b = 0; b < KSEL; ++b)
                cnt += (ids[0][a] == ids[1][b]) ? 1 : 0;
    }

    #pragma unroll
    for (int off = 32; off; off >>= 1) cnt += __shfl_down(cnt, off);
    if (lane == 0) wsum[wave] = cnt;
    __syncthreads();
    if (threadIdx.x == 0)
        atomicAdd(counter, (unsigned)(wsum[0] + wsum[1] + wsum[2] + wsum[3]));
}

__global__ void knn_finalize(const unsigned* __restrict__ counter, float* __restrict__ out)
{
    out[0] = 1.0f - (float)(*counter) / (float)(NROW * KSEL);
}

// ---------------------------------------------------------------- launch
static size_t ws_need(int jc)
{
    size_t o = (size_t)2 * NP * DIM * sizeof(bf16_t) + (size_t)2 * NP * sizeof(float);
    o = (o + 255) & ~(size_t)255;
    o += (size_t)2 * jc * NROW * KSEL * sizeof(uint32_t);
    o += (size_t)2 * jc * NROW * KSEL * sizeof(uint16_t);
    o = (o + 255) & ~(size_t)255;
    o += 256;
    return o;
}

extern "C" void kernel_launch(void* const* d_in, const int* in_sizes, int n_in,
                              void* d_out, int out_size, void* d_ws, size_t ws_size,
                              hipStream_t stream)
{
    (void)in_sizes; (void)n_in; (void)out_size;
    const float* x0 = (const float*)d_in[0];
    const float* x1 = (const float*)d_in[1];
    float* out = (float*)d_out;

    const int jc = (ws_size >= ws_need(8)) ? 8 : 4;

    char* ws = (char*)d_ws;
    size_t off = 0;
    bf16_t* xb  = (bf16_t*)(ws + off); off += (size_t)2 * NP * DIM * sizeof(bf16_t);
    float*  sqh = (float*)(ws + off);  off += (size_t)2 * NP * sizeof(float);
    off = (off + 255) & ~(size_t)255;
    uint32_t* pkey = (uint32_t*)(ws + off); off += (size_t)2 * jc * NROW * KSEL * sizeof(uint32_t);
    uint16_t* pidx = (uint16_t*)(ws + off); off += (size_t)2 * jc * NROW * KSEL * sizeof(uint16_t);
    off = (off + 255) & ~(size_t)255;
    unsigned* counter = (unsigned*)(ws + off);

    knn_convert<<<(2 * NP) / 4, 256, 0, stream>>>(x0, x1, xb, sqh, counter);
    if (jc == 8) {
        knn_topk<8><<<dim3(NP / 64, 8, 2), 256, 0, stream>>>(xb, sqh, pkey, pidx);
        knn_merge_count<8><<<(NROW + 255) / 256, 256, 0, stream>>>(pkey, pidx, counter);
    } else {
        knn_topk<4><<<dim3(NP / 64, 4, 2), 256, 0, stream>>>(xb, sqh, pkey, pidx);
        knn_merge_count<4><<<(NROW + 255) / 256, 256, 0, stream>>>(pkey, pidx, counter);
    }
    knn_finalize<<<1, 1, 0, stream>>>(counter, out);
}

// Round 6
// 469.197 us; speedup vs baseline: 1.0322x; 1.0322x over previous
//
#include <hip/hip_runtime.h>
#include <hip/hip_bf16.h>
#include <stdint.h>

#define NROW 10000
#define DIM 128
#define NP 10048           // rows padded to multiple of 64
#define KSEL 15
#define NTILES (NP / 16)   // 628 j-tiles of 16

typedef __attribute__((ext_vector_type(4))) float f32x4;
typedef __attribute__((ext_vector_type(8))) short s16x8;
using bf16_t = __hip_bfloat16;

// ---------------------------------------------------------------- convert
// One wave per row: f32 -> bf16 (packed u32 stores), sqh = 1024 - 0.5*|x|^2
// (MFMA C-in, bias folded). Pad rows: zero data, sqh = -1e30 -> key clamps
// to 1.0, never top-15.
__global__ __launch_bounds__(256)
void knn_convert(const float* __restrict__ x0, const float* __restrict__ x1,
                 bf16_t* __restrict__ xb, float* __restrict__ sqh,
                 unsigned* __restrict__ counter)
{
    if (blockIdx.x == 0 && threadIdx.x == 0) *counter = 0u;
    const int rg   = blockIdx.x * 4 + (threadIdx.x >> 6);
    const int lane = threadIdx.x & 63;
    if (rg >= 2 * NP) return;
    const int m = rg >= NP ? 1 : 0;
    const int r = rg - m * NP;
    const float* src = m ? x1 : x0;
    uint32_t* dst = (uint32_t*)(xb + ((size_t)m * NP + (size_t)r) * DIM);

    float2 v = make_float2(0.f, 0.f);
    float  s = 0.f;
    if (r < NROW) {
        v = *(const float2*)(src + (size_t)r * DIM + lane * 2);
        s = v.x * v.x + v.y * v.y;
    }
    const uint32_t lo = (uint32_t)__bfloat16_as_ushort(__float2bfloat16(v.x));
    const uint32_t hi = (uint32_t)__bfloat16_as_ushort(__float2bfloat16(v.y));
    dst[lane] = lo | (hi << 16);
    #pragma unroll
    for (int off = 32; off; off >>= 1) s += __shfl_down(s, off);
    if (lane == 0) sqh[m * NP + r] = (r < NROW) ? fmaf(s, -0.5f, 1024.0f) : -1e30f;
}

// ---------------------------------------------------------------- main
// Key = dot(Xj,Xi) + 1024 - 0.5*sq[j] (bias in MFMA C-in), clamped >=1,
// packed as monotonic u32 with 10-bit chunk-local index in the low bits.
// Branchless top-15 per lane via 14x v_med3_u32 + 1 umax in 15 named regs.
// Manual 1-deep pipeline: tile t+1's A-fragments load during tile t's insert.
#define INS(k, hi, lo) asm("v_med3_u32 %0, %1, %2, %0" : "+v"(lo) : "v"(k), "v"(hi))

template<int JC>
__global__ __launch_bounds__(256)
void knn_topk(const bf16_t* __restrict__ xb, const float* __restrict__ sqh,
              uint32_t* __restrict__ pkey, uint16_t* __restrict__ pidx)
{
    __shared__ uint32_t lv[4][64][KSEL];   // keys only; j reconstructed from key bits

    const int m     = blockIdx.z;
    const int chunk = blockIdx.y;
    const int ib    = blockIdx.x * 64;
    const int wave  = threadIdx.x >> 6;
    const int lane  = threadIdx.x & 63;
    const int li    = lane & 15;
    const int g     = lane >> 4;

    const bf16_t* X  = xb + (size_t)m * NP * DIM;
    const float*  SQ = sqh + m * NP;

    const int i  = ib + wave * 16 + li;
    const int ic = i < NROW ? i : NROW - 1;

    // B fragments: lane holds B[k = kk*32 + g*8 + e][col = li] = X[i][k]
    s16x8 bfr[4];
    #pragma unroll
    for (int kk = 0; kk < 4; ++kk)
        bfr[kk] = *(const s16x8*)(X + (size_t)ic * DIM + kk * 32 + g * 8);

    uint32_t q0 = 0, q1 = 0, q2 = 0, q3 = 0, q4 = 0, q5 = 0, q6 = 0, q7 = 0,
             q8 = 0, q9 = 0, q10 = 0, q11 = 0, q12 = 0, q13 = 0, q14 = 0;

    const int t0 = (chunk * NTILES) / JC;
    const int t1 = ((chunk + 1) * NTILES) / JC;

    // Preload tile t0's A-fragments.
    const bf16_t* ap = X + (size_t)(t0 * 16 + li) * DIM + g * 8;
    s16x8 a0 = *(const s16x8*)(ap);
    s16x8 a1 = *(const s16x8*)(ap + 32);
    s16x8 a2 = *(const s16x8*)(ap + 64);
    s16x8 a3 = *(const s16x8*)(ap + 96);

    for (int t = t0; t < t1; ++t) {
        // Prefetch next tile's A-fragments (clamped; last iter reloads, L1-hot).
        const int tn = (t + 1 < t1) ? t + 1 : t;
        const bf16_t* an = X + (size_t)(tn * 16 + li) * DIM + g * 8;
        const s16x8 n0 = *(const s16x8*)(an);
        const s16x8 n1 = *(const s16x8*)(an + 32);
        const s16x8 n2 = *(const s16x8*)(an + 64);
        const s16x8 n3 = *(const s16x8*)(an + 96);

        f32x4 acc = *(const f32x4*)(SQ + t * 16 + g * 4);   // 1024 - 0.5*sq[j]
        acc = __builtin_amdgcn_mfma_f32_16x16x32_bf16(a0, bfr[0], acc, 0, 0, 0);
        acc = __builtin_amdgcn_mfma_f32_16x16x32_bf16(a1, bfr[1], acc, 0, 0, 0);
        acc = __builtin_amdgcn_mfma_f32_16x16x32_bf16(a2, bfr[2], acc, 0, 0, 0);
        acc = __builtin_amdgcn_mfma_f32_16x16x32_bf16(a3, bfr[3], acc, 0, 0, 0);

        // C/D: col = li (the i), row = g*4 + r (the j-local).
        const uint32_t idxb = (uint32_t)((t - t0) << 2);
        #pragma unroll
        for (int r = 0; r < 4; ++r) {
            const float f = fmaxf(acc[r], 1.0f);          // padded j -> never selected
            const uint32_t b = __float_as_uint(f);        // positive float: u32-monotonic
            const uint32_t k = ((b + 512u) & 0xFFFFFC00u) | (idxb + (uint32_t)r);
            INS(k, q13, q14); INS(k, q12, q13); INS(k, q11, q12); INS(k, q10, q11);
            INS(k, q9,  q10); INS(k, q8,  q9);  INS(k, q7,  q8);  INS(k, q6,  q7);
            INS(k, q5,  q6);  INS(k, q4,  q5);  INS(k, q3,  q4);  INS(k, q2,  q3);
            INS(k, q1,  q2);  INS(k, q0,  q1);
            q0 = (q0 > k) ? q0 : k;
        }

        a0 = n0; a1 = n1; a2 = n2; a3 = n3;
    }

    lv[wave][lane][0]  = q0;  lv[wave][lane][1]  = q1;  lv[wave][lane][2]  = q2;
    lv[wave][lane][3]  = q3;  lv[wave][lane][4]  = q4;  lv[wave][lane][5]  = q5;
    lv[wave][lane][6]  = q6;  lv[wave][lane][7]  = q7;  lv[wave][lane][8]  = q8;
    lv[wave][lane][9]  = q9;  lv[wave][lane][10] = q10; lv[wave][lane][11] = q11;
    lv[wave][lane][12] = q12; lv[wave][lane][13] = q13; lv[wave][lane][14] = q14;
    __syncthreads();

    // 4-way merge of the lane-group lists for this i; write sorted 15.
    // j reconstructed from key's low 10 bits + winning group bg.
    if (g == 0 && i < NROW) {
        int p0 = 0, p1 = 0, p2 = 0, p3 = 0;
        uint32_t v0 = lv[wave][li][0];
        uint32_t v1 = lv[wave][16 + li][0];
        uint32_t v2 = lv[wave][32 + li][0];
        uint32_t v3 = lv[wave][48 + li][0];
        uint32_t* ov = pkey + (((size_t)m * JC + chunk) * NROW + i) * KSEL;
        uint16_t* oi = pidx + (((size_t)m * JC + chunk) * NROW + i) * KSEL;
        #pragma unroll
        for (int t = 0; t < KSEL; ++t) {
            uint32_t bv = v0; int bg = 0;
            if (v1 > bv) { bv = v1; bg = 1; }
            if (v2 > bv) { bv = v2; bg = 2; }
            if (v3 > bv) { bv = v3; bg = 3; }
            const uint32_t id = bv & 1023u;
            const int j = (t0 + (int)(id >> 2)) * 16 + bg * 4 + (int)(id & 3u);
            if      (bg == 0) { p0++; v0 = p0 < KSEL ? lv[wave][li][p0]      : 0u; }
            else if (bg == 1) { p1++; v1 = p1 < KSEL ? lv[wave][16 + li][p1] : 0u; }
            else if (bg == 2) { p2++; v2 = p2 < KSEL ? lv[wave][32 + li][p2] : 0u; }
            else              { p3++; v3 = p3 < KSEL ? lv[wave][48 + li][p3] : 0u; }
            ov[t] = bv; oi[t] = (uint16_t)j;
        }
    }
}

// ---------------------------------------------------------------- merge + count
template<int JC>
__global__ __launch_bounds__(256)
void knn_merge_count(const uint32_t* __restrict__ pkey, const uint16_t* __restrict__ pidx,
                     unsigned* __restrict__ counter)
{
    __shared__ int wsum[4];
    const int i    = blockIdx.x * 256 + threadIdx.x;
    const int lane = threadIdx.x & 63;
    const int wave = threadIdx.x >> 6;

    int cnt = 0;
    if (i < NROW) {
        int ids[2][KSEL];
        #pragma unroll
        for (int m = 0; m < 2; ++m) {
            const uint32_t* pv = pkey + (size_t)m * JC * NROW * KSEL;
            const uint16_t* px = pidx + (size_t)m * JC * NROW * KSEL;
            uint32_t v[JC]; int p[JC];
            #pragma unroll
            for (int gg = 0; gg < JC; ++gg) {
                p[gg] = 0;
                v[gg] = pv[((size_t)gg * NROW + i) * KSEL];
            }
            #pragma unroll
            for (int t = 0; t < KSEL; ++t) {
                uint32_t bv = v[0]; int bg = 0;
                #pragma unroll
                for (int gg = 1; gg < JC; ++gg) if (v[gg] > bv) { bv = v[gg]; bg = gg; }
                int j = 0;
                #pragma unroll
                for (int gg = 0; gg < JC; ++gg)
                    if (gg == bg) j = (int)px[((size_t)gg * NROW + i) * KSEL + p[gg]];
                ids[m][t] = j;
                #pragma unroll
                for (int gg = 0; gg < JC; ++gg)
                    if (gg == bg) {
                        p[gg]++;
                        v[gg] = p[gg] < KSEL ? pv[((size_t)gg * NROW + i) * KSEL + p[gg]] : 0u;
                    }
            }
        }
        #pragma unroll
        for (int a = 0; a < KSEL; ++a)
            #pragma unroll
            for (int b = 0; b < KSEL; ++b)
                cnt += (ids[0][a] == ids[1][b]) ? 1 : 0;
    }

    #pragma unroll
    for (int off = 32; off; off >>= 1) cnt += __shfl_down(cnt, off);
    if (lane == 0) wsum[wave] = cnt;
    __syncthreads();
    if (threadIdx.x == 0)
        atomicAdd(counter, (unsigned)(wsum[0] + wsum[1] + wsum[2] + wsum[3]));
}

__global__ void knn_finalize(const unsigned* __restrict__ counter, float* __restrict__ out)
{
    out[0] = 1.0f - (float)(*counter) / (float)(NROW * KSEL);
}

// ---------------------------------------------------------------- launch
static size_t ws_need(int jc)
{
    size_t o = (size_t)2 * NP * DIM * sizeof(bf16_t) + (size_t)2 * NP * sizeof(float);
    o = (o + 255) & ~(size_t)255;
    o += (size_t)2 * jc * NROW * KSEL * sizeof(uint32_t);
    o += (size_t)2 * jc * NROW * KSEL * sizeof(uint16_t);
    o = (o + 255) & ~(size_t)255;
    o += 256;
    return o;
}

extern "C" void kernel_launch(void* const* d_in, const int* in_sizes, int n_in,
                              void* d_out, int out_size, void* d_ws, size_t ws_size,
                              hipStream_t stream)
{
    (void)in_sizes; (void)n_in; (void)out_size;
    const float* x0 = (const float*)d_in[0];
    const float* x1 = (const float*)d_in[1];
    float* out = (float*)d_out;

    const int jc = (ws_size >= ws_need(8)) ? 8 : 4;

    char* ws = (char*)d_ws;
    size_t off = 0;
    bf16_t* xb  = (bf16_t*)(ws + off); off += (size_t)2 * NP * DIM * sizeof(bf16_t);
    float*  sqh = (float*)(ws + off);  off += (size_t)2 * NP * sizeof(float);
    off = (off + 255) & ~(size_t)255;
    uint32_t* pkey = (uint32_t*)(ws + off); off += (size_t)2 * jc * NROW * KSEL * sizeof(uint32_t);
    uint16_t* pidx = (uint16_t*)(ws + off); off += (size_t)2 * jc * NROW * KSEL * sizeof(uint16_t);
    off = (off + 255) & ~(size_t)255;
    unsigned* counter = (unsigned*)(ws + off);

    knn_convert<<<(2 * NP) / 4, 256, 0, stream>>>(x0, x1, xb, sqh, counter);
    if (jc == 8) {
        knn_topk<8><<<dim3(NP / 64, 8, 2), 256, 0, stream>>>(xb, sqh, pkey, pidx);
        knn_merge_count<8><<<(NROW + 255) / 256, 256, 0, stream>>>(pkey, pidx, counter);
    } else {
        knn_topk<4><<<dim3(NP / 64, 4, 2), 256, 0, stream>>>(xb, sqh, pkey, pidx);
        knn_merge_count<4><<<(NROW + 255) / 256, 256, 0, stream>>>(pkey, pidx, counter);
    }
    knn_finalize<<<1, 1, 0, stream>>>(counter, out);
}

// Round 7
// 202.596 us; speedup vs baseline: 2.3904x; 2.3159x over previous
//
#include <hip/hip_runtime.h>
#include <hip/hip_bf16.h>
#include <stdint.h>

#define NROW 10000
#define DIM 128
#define NP 10240          // rows padded to 640 tiles of 16 (divisible by JC=8 chunks)
#define KSEL 15
#define NTILES (NP / 16)  // 640

typedef __attribute__((ext_vector_type(4))) float f32x4;
typedef __attribute__((ext_vector_type(8))) short s16x8;
using bf16_t = __hip_bfloat16;

// ---------------------------------------------------------------- convert
// One wave per row. Writes X in MFMA-fragment-packed layout:
//   elem e = kk*32 + g*8 + pos of row r  ->  ((tile*4+kk)*64 + g*16 + (r&15))*8 + pos
// so an A-fragment load in knn_topk is base + lane*16B (fully coalesced), and
// B-fragments come from the same layout. Also sqh = 1024 - 0.5*|x|^2 (MFMA C-in).
// Pad rows: zero data, sqh = 1.0 -> key ~1.0, never beats real keys (~820+).
__global__ __launch_bounds__(256)
void knn_convert(const float* __restrict__ x0, const float* __restrict__ x1,
                 bf16_t* __restrict__ xp, float* __restrict__ sqh,
                 unsigned* __restrict__ counter)
{
    if (blockIdx.x == 0 && threadIdx.x == 0) *counter = 0u;
    const int rg   = blockIdx.x * 4 + (threadIdx.x >> 6);
    const int lane = threadIdx.x & 63;
    if (rg >= 2 * NP) return;
    const int m = rg >= NP ? 1 : 0;
    const int r = rg - m * NP;
    const float* src = m ? x1 : x0;

    float2 v = make_float2(0.f, 0.f);
    float  s = 0.f;
    if (r < NROW) {
        v = *(const float2*)(src + (size_t)r * DIM + lane * 2);
        s = v.x * v.x + v.y * v.y;
    }
    const uint32_t pk = (uint32_t)__bfloat16_as_ushort(__float2bfloat16(v.x))
                      | ((uint32_t)__bfloat16_as_ushort(__float2bfloat16(v.y)) << 16);
    const int e   = lane * 2;
    const int kk  = e >> 5;
    const int gg  = (e >> 3) & 3;
    const int pos = e & 7;
    const size_t off = ((((size_t)m * NTILES + (r >> 4)) * 4 + kk) * 64
                        + (size_t)(gg * 16 + (r & 15))) * 8 + pos;   // even
    *(uint32_t*)(xp + off) = pk;
    #pragma unroll
    for (int o = 32; o; o >>= 1) s += __shfl_down(s, o);
    if (lane == 0) sqh[m * NP + r] = (r < NROW) ? fmaf(s, -0.5f, 1024.0f) : 1.0f;
}

// ---------------------------------------------------------------- main
// Key = dot(Xj,Xi) + 1024 - 0.5*sq[j] (bias in MFMA C-in), packed as monotonic
// u32 with 10-bit chunk-local index in the low bits. Branchless top-15 per lane
// via 14x v_med3_u32 + 1 umax in 15 named regs. 2 tiles/iter with 2-tile-ahead
// register prefetch ({sq, A-frags} issued oldest-first -> counted vmcnt, no
// full drains in steady state).
#define INS(k, hi, lo) asm("v_med3_u32 %0, %1, %2, %0" : "+v"(lo) : "v"(k), "v"(hi))

#define INSERT4(acc, idxb)                                                        \
    do {                                                                          \
        _Pragma("unroll")                                                         \
        for (int r_ = 0; r_ < 4; ++r_) {                                          \
            const uint32_t b_ = __float_as_uint((acc)[r_]);                       \
            const uint32_t k_ = ((b_ + 512u) & 0xFFFFFC00u) | ((idxb) + (uint32_t)r_); \
            INS(k_, q13, q14); INS(k_, q12, q13); INS(k_, q11, q12);              \
            INS(k_, q10, q11); INS(k_, q9,  q10); INS(k_, q8,  q9);               \
            INS(k_, q7,  q8);  INS(k_, q6,  q7);  INS(k_, q5,  q6);               \
            INS(k_, q4,  q5);  INS(k_, q3,  q4);  INS(k_, q2,  q3);               \
            INS(k_, q1,  q2);  INS(k_, q0,  q1);                                  \
            q0 = (q0 > k_) ? q0 : k_;                                             \
        }                                                                         \
    } while (0)

template<int JC>
__global__ __launch_bounds__(256)
void knn_topk(const bf16_t* __restrict__ xp, const float* __restrict__ sqh,
              uint32_t* __restrict__ pkey, uint16_t* __restrict__ pidx)
{
    __shared__ uint32_t lv[4][64][KSEL];   // keys only; j reconstructed from key bits

    const int m     = blockIdx.z;
    const int chunk = blockIdx.y;
    const int ib    = blockIdx.x * 64;
    const int wave  = threadIdx.x >> 6;
    const int lane  = threadIdx.x & 63;
    const int li    = lane & 15;
    const int g     = lane >> 4;

    const bf16_t* XP = xp + (size_t)m * NP * DIM;
    const float*  SQ = sqh + m * NP;

    const int i  = ib + wave * 16 + li;
    const int ti = (ib >> 4) + wave;       // i-tile index for B-fragments

    // B fragments from packed layout: lane holds B[k=kk*32+g*8+e][col=li] = X[i][k]
    s16x8 bfr[4];
    #pragma unroll
    for (int kk = 0; kk < 4; ++kk)
        bfr[kk] = *(const s16x8*)(XP + (((size_t)ti * 4 + kk) * 64 + (size_t)(g * 16 + li)) * 8);

    uint32_t q0 = 0, q1 = 0, q2 = 0, q3 = 0, q4 = 0, q5 = 0, q6 = 0, q7 = 0,
             q8 = 0, q9 = 0, q10 = 0, q11 = 0, q12 = 0, q13 = 0, q14 = 0;

    const int TPC = NTILES / JC;           // tiles per chunk (80 at JC=8, even)
    const int t0  = chunk * TPC;

    const bf16_t* tb  = XP + (size_t)t0 * (4 * 64 * 8) + (size_t)lane * 8;  // lane's A-frag base
    const float*  sqb = SQ + t0 * 16 + g * 4;

    // Preload tiles 0 and 1 of this chunk (sq first -> oldest -> counted waits).
    f32x4 sA = *(const f32x4*)(sqb);
    s16x8 a0 = *(const s16x8*)(tb);
    s16x8 a1 = *(const s16x8*)(tb + 512);
    s16x8 a2 = *(const s16x8*)(tb + 1024);
    s16x8 a3 = *(const s16x8*)(tb + 1536);
    f32x4 sB = *(const f32x4*)(sqb + 16);
    s16x8 a4 = *(const s16x8*)(tb + 2048);
    s16x8 a5 = *(const s16x8*)(tb + 2048 + 512);
    s16x8 a6 = *(const s16x8*)(tb + 2048 + 1024);
    s16x8 a7 = *(const s16x8*)(tb + 2048 + 1536);

    for (int p = 0; p < TPC / 2; ++p) {
        const int lt = 2 * p;
        // ---- slot A: prefetch tile lt+2, compute tile lt
        {
            const int pf = (lt + 2 < TPC) ? lt + 2 : lt;
            const f32x4 ns = *(const f32x4*)(sqb + pf * 16);
            const bf16_t* pb = tb + (size_t)pf * 2048;
            const s16x8 n0 = *(const s16x8*)(pb);
            const s16x8 n1 = *(const s16x8*)(pb + 512);
            const s16x8 n2 = *(const s16x8*)(pb + 1024);
            const s16x8 n3 = *(const s16x8*)(pb + 1536);

            f32x4 acc = sA;
            acc = __builtin_amdgcn_mfma_f32_16x16x32_bf16(a0, bfr[0], acc, 0, 0, 0);
            acc = __builtin_amdgcn_mfma_f32_16x16x32_bf16(a1, bfr[1], acc, 0, 0, 0);
            acc = __builtin_amdgcn_mfma_f32_16x16x32_bf16(a2, bfr[2], acc, 0, 0, 0);
            acc = __builtin_amdgcn_mfma_f32_16x16x32_bf16(a3, bfr[3], acc, 0, 0, 0);
            INSERT4(acc, (uint32_t)(lt << 2));
            a0 = n0; a1 = n1; a2 = n2; a3 = n3; sA = ns;
        }
        // ---- slot B: prefetch tile lt+3, compute tile lt+1
        {
            const int pf = (lt + 3 < TPC) ? lt + 3 : lt + 1;
            const f32x4 ns = *(const f32x4*)(sqb + pf * 16);
            const bf16_t* pb = tb + (size_t)pf * 2048;
            const s16x8 n4 = *(const s16x8*)(pb);
            const s16x8 n5 = *(const s16x8*)(pb + 512);
            const s16x8 n6 = *(const s16x8*)(pb + 1024);
            const s16x8 n7 = *(const s16x8*)(pb + 1536);

            f32x4 acc = sB;
            acc = __builtin_amdgcn_mfma_f32_16x16x32_bf16(a4, bfr[0], acc, 0, 0, 0);
            acc = __builtin_amdgcn_mfma_f32_16x16x32_bf16(a5, bfr[1], acc, 0, 0, 0);
            acc = __builtin_amdgcn_mfma_f32_16x16x32_bf16(a6, bfr[2], acc, 0, 0, 0);
            acc = __builtin_amdgcn_mfma_f32_16x16x32_bf16(a7, bfr[3], acc, 0, 0, 0);
            INSERT4(acc, (uint32_t)((lt + 1) << 2));
            a4 = n4; a5 = n5; a6 = n6; a7 = n7; sB = ns;
        }
    }

    lv[wave][lane][0]  = q0;  lv[wave][lane][1]  = q1;  lv[wave][lane][2]  = q2;
    lv[wave][lane][3]  = q3;  lv[wave][lane][4]  = q4;  lv[wave][lane][5]  = q5;
    lv[wave][lane][6]  = q6;  lv[wave][lane][7]  = q7;  lv[wave][lane][8]  = q8;
    lv[wave][lane][9]  = q9;  lv[wave][lane][10] = q10; lv[wave][lane][11] = q11;
    lv[wave][lane][12] = q12; lv[wave][lane][13] = q13; lv[wave][lane][14] = q14;
    __syncthreads();

    // 4-way merge of the lane-group lists for this i; write sorted 15.
    if (g == 0 && i < NROW) {
        int p0 = 0, p1 = 0, p2 = 0, p3 = 0;
        uint32_t v0 = lv[wave][li][0];
        uint32_t v1 = lv[wave][16 + li][0];
        uint32_t v2 = lv[wave][32 + li][0];
        uint32_t v3 = lv[wave][48 + li][0];
        uint32_t* ov = pkey + (((size_t)m * JC + chunk) * NROW + i) * KSEL;
        uint16_t* oi = pidx + (((size_t)m * JC + chunk) * NROW + i) * KSEL;
        #pragma unroll
        for (int t = 0; t < KSEL; ++t) {
            uint32_t bv = v0; int bg = 0;
            if (v1 > bv) { bv = v1; bg = 1; }
            if (v2 > bv) { bv = v2; bg = 2; }
            if (v3 > bv) { bv = v3; bg = 3; }
            const uint32_t id = bv & 1023u;
            const int j = (t0 + (int)(id >> 2)) * 16 + bg * 4 + (int)(id & 3u);
            if      (bg == 0) { p0++; v0 = p0 < KSEL ? lv[wave][li][p0]      : 0u; }
            else if (bg == 1) { p1++; v1 = p1 < KSEL ? lv[wave][16 + li][p1] : 0u; }
            else if (bg == 2) { p2++; v2 = p2 < KSEL ? lv[wave][32 + li][p2] : 0u; }
            else              { p3++; v3 = p3 < KSEL ? lv[wave][48 + li][p3] : 0u; }
            ov[t] = bv; oi[t] = (uint16_t)j;
        }
    }
}

// ---------------------------------------------------------------- merge + count
template<int JC>
__global__ __launch_bounds__(256)
void knn_merge_count(const uint32_t* __restrict__ pkey, const uint16_t* __restrict__ pidx,
                     unsigned* __restrict__ counter)
{
    __shared__ int wsum[4];
    const int i    = blockIdx.x * 256 + threadIdx.x;
    const int lane = threadIdx.x & 63;
    const int wave = threadIdx.x >> 6;

    int cnt = 0;
    if (i < NROW) {
        int ids[2][KSEL];
        #pragma unroll
        for (int m = 0; m < 2; ++m) {
            const uint32_t* pv = pkey + (size_t)m * JC * NROW * KSEL;
            const uint16_t* px = pidx + (size_t)m * JC * NROW * KSEL;
            uint32_t v[JC]; int p[JC];
            #pragma unroll
            for (int gg = 0; gg < JC; ++gg) {
                p[gg] = 0;
                v[gg] = pv[((size_t)gg * NROW + i) * KSEL];
            }
            #pragma unroll
            for (int t = 0; t < KSEL; ++t) {
                uint32_t bv = v[0]; int bg = 0;
                #pragma unroll
                for (int gg = 1; gg < JC; ++gg) if (v[gg] > bv) { bv = v[gg]; bg = gg; }
                int j = 0;
                #pragma unroll
                for (int gg = 0; gg < JC; ++gg)
                    if (gg == bg) j = (int)px[((size_t)gg * NROW + i) * KSEL + p[gg]];
                ids[m][t] = j;
                #pragma unroll
                for (int gg = 0; gg < JC; ++gg)
                    if (gg == bg) {
                        p[gg]++;
                        v[gg] = p[gg] < KSEL ? pv[((size_t)gg * NROW + i) * KSEL + p[gg]] : 0u;
                    }
            }
        }
        #pragma unroll
        for (int a = 0; a < KSEL; ++a)
            #pragma unroll
            for (int b = 0; b < KSEL; ++b)
                cnt += (ids[0][a] == ids[1][b]) ? 1 : 0;
    }

    #pragma unroll
    for (int off = 32; off; off >>= 1) cnt += __shfl_down(cnt, off);
    if (lane == 0) wsum[wave] = cnt;
    __syncthreads();
    if (threadIdx.x == 0)
        atomicAdd(counter, (unsigned)(wsum[0] + wsum[1] + wsum[2] + wsum[3]));
}

__global__ void knn_finalize(const unsigned* __restrict__ counter, float* __restrict__ out)
{
    out[0] = 1.0f - (float)(*counter) / (float)(NROW * KSEL);
}

// ---------------------------------------------------------------- launch
static size_t ws_need(int jc)
{
    size_t o = (size_t)2 * NP * DIM * sizeof(bf16_t) + (size_t)2 * NP * sizeof(float);
    o = (o + 255) & ~(size_t)255;
    o += (size_t)2 * jc * NROW * KSEL * sizeof(uint32_t);
    o += (size_t)2 * jc * NROW * KSEL * sizeof(uint16_t);
    o = (o + 255) & ~(size_t)255;
    o += 256;
    return o;
}

extern "C" void kernel_launch(void* const* d_in, const int* in_sizes, int n_in,
                              void* d_out, int out_size, void* d_ws, size_t ws_size,
                              hipStream_t stream)
{
    (void)in_sizes; (void)n_in; (void)out_size;
    const float* x0 = (const float*)d_in[0];
    const float* x1 = (const float*)d_in[1];
    float* out = (float*)d_out;

    const int jc = (ws_size >= ws_need(8)) ? 8 : 4;

    char* ws = (char*)d_ws;
    size_t off = 0;
    bf16_t* xp  = (bf16_t*)(ws + off); off += (size_t)2 * NP * DIM * sizeof(bf16_t);
    float*  sqh = (float*)(ws + off);  off += (size_t)2 * NP * sizeof(float);
    off = (off + 255) & ~(size_t)255;
    uint32_t* pkey = (uint32_t*)(ws + off); off += (size_t)2 * jc * NROW * KSEL * sizeof(uint32_t);
    uint16_t* pidx = (uint16_t*)(ws + off); off += (size_t)2 * jc * NROW * KSEL * sizeof(uint16_t);
    off = (off + 255) & ~(size_t)255;
    unsigned* counter = (unsigned*)(ws + off);

    knn_convert<<<(2 * NP) / 4, 256, 0, stream>>>(x0, x1, xp, sqh, counter);
    if (jc == 8) {
        knn_topk<8><<<dim3(NP / 64, 8, 2), 256, 0, stream>>>(xp, sqh, pkey, pidx);
        knn_merge_count<8><<<(NROW + 255) / 256, 256, 0, stream>>>(pkey, pidx, counter);
    } else {
        knn_topk<4><<<dim3(NP / 64, 4, 2), 256, 0, stream>>>(xp, sqh, pkey, pidx);
        knn_merge_count<4><<<(NROW + 255) / 256, 256, 0, stream>>>(pkey, pidx, counter);
    }
    knn_finalize<<<1, 1, 0, stream>>>(counter, out);
}